// Round 14
// baseline (272.179 us; speedup 1.0000x reference)
//
#include <hip/hip_runtime.h>
#include <hip/hip_bf16.h>

#define NN 10000
#define NE 640000
#define D 128
#define NF (NN * D)
#define WS 136   // padded bf16 row stride: 272 B = 16B-aligned, 2-way-free LDS banks
#define WBYTES (D * WS * 2)      // 34816 B per W^T matrix
#define WCHUNKS (WBYTES / 1024)  // 34 async 1KB wave-chunks
#define NBLK 250                 // hist blocks (2560 edges each -> short critical path)
#define EPB (NE / NBLK)          // 2560 edges per hist block (10 iters of 256)
#define MPAD 1000000             // padded meta capacity: 640k + 10k*31 + slack

typedef __bf16 bf16x8 __attribute__((ext_vector_type(8)));
typedef __bf16 bf16x2 __attribute__((ext_vector_type(2)));
typedef float f32x4 __attribute__((ext_vector_type(4)));

// async global->LDS, 16B per lane, 1 KB per wave-call [m97-verified width=16]
__device__ __forceinline__ void async_copy16(const void* g, void* l) {
    __builtin_amdgcn_global_load_lds(
        (const __attribute__((address_space(1))) unsigned int*)g,
        (__attribute__((address_space(3))) unsigned int*)l, 16, 0, 0);
}

// packed bf16x2 (as uint dword) -> float2 via v_cvt_pk_f32_bf16
__device__ __forceinline__ float2 bf2_to_f2(unsigned int dw) {
    return __bfloat1622float2(*(const __hip_bfloat162*)&dw);
}

// ---------------- fused: LDS histogram | x->bf16 | W->bf16 transposed ----------------
// blocks [0,250): packed LDS histogram (2 nodes/int; per-block counts < 2^16)
// blocks [250,2750): x -> bf16 ;  blocks [2750,2763): W -> Wt[n][k]

__global__ __launch_bounds__(256) void hist_prep_kernel(
    const int* __restrict__ ei, int* __restrict__ cnt_blk, int* __restrict__ local_rank,
    const float2* __restrict__ x2, bf16x2* __restrict__ xbf,
    const float* __restrict__ mW1, const float* __restrict__ mW2,
    const float* __restrict__ sW1, const float* __restrict__ sW2,
    const float* __restrict__ scW1, __bf16* __restrict__ wt) {
    __shared__ unsigned int hist[NN / 2];   // 20 KB, 2 nodes per int
    int b = blockIdx.x, t = threadIdx.x;
    if (b < NBLK) {
        for (int i = t; i < NN / 2; i += 256) hist[i] = 0u;
        __syncthreads();
        int base = b * EPB;
#pragma unroll 5
        for (int i = 0; i < EPB / 256; i++) {
            int e = base + i * 256 + t;
            int d = ei[NE + e];
            int sh = (d & 1) * 16;
            unsigned int old = atomicAdd(&hist[d >> 1], 1u << sh);
            local_rank[e] = (old >> sh) & 0xFFFFu;
        }
        __syncthreads();
        for (int i = t; i < NN; i += 256)
            cnt_blk[b * NN + i] = (hist[i >> 1] >> ((i & 1) * 16)) & 0xFFFFu;
    } else if (b < NBLK + 2500) {
        int i = (b - NBLK) * 256 + t;   // NF/2 = 640000
        float2 v = x2[i];
        bf16x2 o;
        o.x = (__bf16)v.x;
        o.y = (__bf16)v.y;
        xbf[i] = o;
    } else {
        int m = b - (NBLK + 2500);  // 0-2 msg_W1, 3-5 msg_W2, 6-8 self_W1, 9-11 self_W2, 12 score_W1
        const float* W = (m < 3)   ? mW1 + (size_t)m * D * D
                       : (m < 6)   ? mW2 + (size_t)(m - 3) * D * D
                       : (m < 9)   ? sW1 + (size_t)(m - 6) * D * D
                       : (m < 12)  ? sW2 + (size_t)(m - 9) * D * D
                                   : scW1;
        __bf16* o = wt + (size_t)m * D * WS;
        for (int i = t; i < D * D; i += 256) {
            int k = i >> 7, n = i & 127;
            o[n * WS + k] = (__bf16)W[i];
        }
    }
}

// per-node prefix over blocks (in place) + total count; fully coalesced
__global__ void colsum_kernel(int* __restrict__ cnt_blk, int* __restrict__ cnt) {
    int n = blockIdx.x * 256 + threadIdx.x;
    if (n >= NN) return;
    int acc = 0;
#pragma unroll 5
    for (int b = 0; b < NBLK; b++) {
        int v = cnt_blk[b * NN + n];
        cnt_blk[b * NN + n] = acc;
        acc += v;
    }
    cnt[n] = acc;
}

// scan over PADDED counts (each row rounded up to 32) -> guard-free aggregate
__global__ void scan_kernel(const int* __restrict__ cnt, int* __restrict__ row_ptr) {
    __shared__ int lds[256];
    int t = threadIdx.x;
    const int CH = (NN + 255) / 256;  // 40
    int base = t * CH;
    int s = 0;
    for (int i = 0; i < CH; i++) {
        int idx = base + i;
        if (idx < NN) s += (cnt[idx] + 31) & ~31;
    }
    lds[t] = s;
    __syncthreads();
    for (int off = 1; off < 256; off <<= 1) {
        int v = (t >= off) ? lds[t - off] : 0;
        __syncthreads();
        lds[t] += v;
        __syncthreads();
    }
    int run = (t == 0) ? 0 : lds[t - 1];
    for (int i = 0; i < CH; i++) {
        int idx = base + i;
        if (idx < NN) {
            row_ptr[idx] = run;
            run += (cnt[idx] + 31) & ~31;
        }
    }
    if (t == 255) row_ptr[NN] = lds[255];
}

// atomic-free scatter into the padded CSR (pad slots pre-zeroed by memset)
__global__ void scatter_kernel(const int* __restrict__ ei, const float* __restrict__ conf,
                               const int* __restrict__ local_rank,
                               const int* __restrict__ cnt_blk,
                               const int* __restrict__ row_ptr, float2* __restrict__ meta) {
    int e = blockIdx.x * 256 + threadIdx.x;
    if (e >= NE) return;
    int s = ei[e];
    int d = ei[NE + e];
    int blk = e / EPB;
    int pos = row_ptr[d] + cnt_blk[blk * NN + d] + local_rank[e];
    meta[pos] = make_float2(__int_as_float(s), expf(-fabsf(conf[s] - conf[d])));
}

// ---------------- fused 2-layer MLP via bf16 MFMA ----------------

__global__ __launch_bounds__(128) void mlp_pair_mfma(
    const __bf16* __restrict__ Abf,
    const __bf16* __restrict__ Wt1a, const float* __restrict__ b1a,
    const __bf16* __restrict__ Wt2a, const float* __restrict__ b2a, __bf16* __restrict__ Mbf,
    const __bf16* __restrict__ Wt1b, const float* __restrict__ b1b,
    const __bf16* __restrict__ Wt2b, const float* __restrict__ b2b, float* __restrict__ Cself) {
    const __bf16* Wt1 = blockIdx.y ? Wt1b : Wt1a;
    const float* b1 = blockIdx.y ? b1b : b1a;
    const __bf16* Wt2 = blockIdx.y ? Wt2b : Wt2a;
    const float* b2 = blockIdx.y ? b2b : b2a;

    __shared__ __align__(16) __bf16 Wl[2][D * WS];    // 2 x 34816 B
    __shared__ __align__(16) __bf16 Tl[2][16 * WS];   // 4352 B per wave
    int t = threadIdx.x;
    int wid = t >> 6, lane = t & 63;
    int m16 = lane & 15, q = lane >> 4;

    for (int c = wid; c < WCHUNKS; c += 2)
        async_copy16((const char*)Wt1 + c * 1024 + lane * 16,
                     (char*)&Wl[0][0] + c * 1024 + lane * 16);

    int row0 = blockIdx.x * 32 + wid * 16;
    int arow = min(row0 + m16, NN - 1);

    bf16x8 af[4];
#pragma unroll
    for (int kk = 0; kk < 4; kk++) af[kk] = *(const bf16x8*)&Abf[(size_t)arow * D + kk * 32 + q * 8];
    float b1v[8], b2v[8];
#pragma unroll
    for (int ct = 0; ct < 8; ct++) { b1v[ct] = b1[ct * 16 + m16]; b2v[ct] = b2[ct * 16 + m16]; }

    __syncthreads();   // drains W1 staging

    for (int c = wid; c < WCHUNKS; c += 2)   // W2 staging overlaps stage-1 MFMAs
        async_copy16((const char*)Wt2 + c * 1024 + lane * 16,
                     (char*)&Wl[1][0] + c * 1024 + lane * 16);

    f32x4 acc[8];
#pragma unroll
    for (int ct = 0; ct < 8; ct++) acc[ct] = (f32x4){0.f, 0.f, 0.f, 0.f};
#pragma unroll
    for (int kk = 0; kk < 4; kk++) {
#pragma unroll
        for (int ct = 0; ct < 8; ct++) {
            bf16x8 b = *(const bf16x8*)&Wl[0][(ct * 16 + m16) * WS + kk * 32 + q * 8];
            acc[ct] = __builtin_amdgcn_mfma_f32_16x16x32_bf16(af[kk], b, acc[ct], 0, 0, 0);
        }
    }
#pragma unroll
    for (int ct = 0; ct < 8; ct++) {
#pragma unroll
        for (int r = 0; r < 4; r++) {
            float v = fmaxf(acc[ct][r] + b1v[ct], 0.f);
            Tl[wid][(q * 4 + r) * WS + ct * 16 + m16] = (__bf16)v;
        }
    }
    __syncthreads();   // drains W2 staging; T is wave-private

#pragma unroll
    for (int ct = 0; ct < 8; ct++) acc[ct] = (f32x4){0.f, 0.f, 0.f, 0.f};
#pragma unroll
    for (int kk = 0; kk < 4; kk++) {
        bf16x8 a = *(const bf16x8*)&Tl[wid][m16 * WS + kk * 32 + q * 8];
#pragma unroll
        for (int ct = 0; ct < 8; ct++) {
            bf16x8 b = *(const bf16x8*)&Wl[1][(ct * 16 + m16) * WS + kk * 32 + q * 8];
            acc[ct] = __builtin_amdgcn_mfma_f32_16x16x32_bf16(a, b, acc[ct], 0, 0, 0);
        }
    }
    if (blockIdx.y == 0) {
#pragma unroll
        for (int ct = 0; ct < 8; ct++) {
#pragma unroll
            for (int r = 0; r < 4; r++) {
                int row = row0 + q * 4 + r;
                if (row < NN) Mbf[(size_t)row * D + ct * 16 + m16] = (__bf16)(acc[ct][r] + b2v[ct]);
            }
        }
    } else {
#pragma unroll
        for (int ct = 0; ct < 8; ct++) {
#pragma unroll
            for (int r = 0; r < 4; r++) {
                int row = row0 + q * 4 + r;
                if (row < NN) Cself[(size_t)row * D + ct * 16 + m16] = acc[ct][r] + b2v[ct];
            }
        }
    }
}

// ---------------- CSR aggregate: padded rows, shuffle-broadcast meta ----------------
// 32-edge chunks, single prefetch (r11 structure). bf16 unpack via
// v_cvt_pk_f32_bf16 (1 instr / dword) instead of shift+and — halves the
// per-edge VALU and shortens the serial chunk chain.

__global__ __launch_bounds__(256) void aggregate_kernel(
    const uint4* __restrict__ Mbf4, const float4* __restrict__ Mself4,
    const int* __restrict__ row_ptr, const float2* __restrict__ meta,
    float4* __restrict__ out4, bf16x8* __restrict__ stbf8) {
    int wid = (blockIdx.x * 256 + threadIdx.x) >> 6;   // node id (2500*4 = NN)
    int lane = threadIdx.x & 63;
    int q = lane >> 4, l4 = lane & 15, l5 = lane & 31;
    int beg = row_ptr[wid], end = row_ptr[wid + 1];
    float a[8] = {0.f, 0.f, 0.f, 0.f, 0.f, 0.f, 0.f, 0.f};
    float2 mcur = meta[beg + l5];            // chunk 0 meta (slack-safe)
    for (int j = beg; j < end; j += 32) {
        float2 mnext = meta[j + 32 + l5];    // prefetch next chunk (slack-safe)
        int srcid[8];
        float wgt[8];
#pragma unroll
        for (int u = 0; u < 8; u++) {
            int sl = 4 * u + q;
            srcid[u] = __float_as_int(__shfl(mcur.x, sl));
            wgt[u] = __shfl(mcur.y, sl);
        }
        uint4 g[8];
#pragma unroll
        for (int u = 0; u < 8; u++) g[u] = Mbf4[(size_t)srcid[u] * 16 + l4];
#pragma unroll
        for (int u = 0; u < 8; u++) {
            float w = wgt[u];
            float2 p0 = bf2_to_f2(g[u].x);
            float2 p1 = bf2_to_f2(g[u].y);
            float2 p2 = bf2_to_f2(g[u].z);
            float2 p3 = bf2_to_f2(g[u].w);
            a[0] = fmaf(w, p0.x, a[0]);
            a[1] = fmaf(w, p0.y, a[1]);
            a[2] = fmaf(w, p1.x, a[2]);
            a[3] = fmaf(w, p1.y, a[3]);
            a[4] = fmaf(w, p2.x, a[4]);
            a[5] = fmaf(w, p2.y, a[5]);
            a[6] = fmaf(w, p3.x, a[6]);
            a[7] = fmaf(w, p3.y, a[7]);
        }
        mcur = mnext;
    }
#pragma unroll
    for (int i = 0; i < 8; i++) {
        a[i] += __shfl_xor(a[i], 16);
        a[i] += __shfl_xor(a[i], 32);
    }
    if (q == 0) {   // lanes 0..15: features 8*l4 .. 8*l4+7, canonical
        float4 sv0 = Mself4[(size_t)wid * 32 + 2 * l4];
        float4 sv1 = Mself4[(size_t)wid * 32 + 2 * l4 + 1];
        float4 r0, r1;
        r0.x = fmaxf(a[0] + sv0.x, 0.f);
        r0.y = fmaxf(a[1] + sv0.y, 0.f);
        r0.z = fmaxf(a[2] + sv0.z, 0.f);
        r0.w = fmaxf(a[3] + sv0.w, 0.f);
        r1.x = fmaxf(a[4] + sv1.x, 0.f);
        r1.y = fmaxf(a[5] + sv1.y, 0.f);
        r1.z = fmaxf(a[6] + sv1.z, 0.f);
        r1.w = fmaxf(a[7] + sv1.w, 0.f);
        out4[(size_t)wid * 32 + 2 * l4] = r0;
        out4[(size_t)wid * 32 + 2 * l4 + 1] = r1;
        bf16x8 hb;
        hb[0] = (__bf16)r0.x; hb[1] = (__bf16)r0.y;
        hb[2] = (__bf16)r0.z; hb[3] = (__bf16)r0.w;
        hb[4] = (__bf16)r1.x; hb[5] = (__bf16)r1.y;
        hb[6] = (__bf16)r1.z; hb[7] = (__bf16)r1.w;
        stbf8[(size_t)wid * 16 + l4] = hb;
    }
}

// ---------------- fused scoring (MFMA) + softmax + weighted sum ----------------

__global__ __launch_bounds__(256) void score_finalize_mfma(
    const __bf16* __restrict__ stbf, const float* __restrict__ st,
    const __bf16* __restrict__ Wt1, const float* __restrict__ b1,
    const float* __restrict__ w2, const float* __restrict__ b2,
    float* __restrict__ out, float* __restrict__ lw_out) {
    __shared__ __align__(16) __bf16 Wl[D * WS];   // 34816 B
    __shared__ float sc_l[3][64];
    __shared__ float lw_l[3][64];
    int t = threadIdx.x;
    int wid = t >> 6, lane = t & 63;
    int m16 = lane & 15, q = lane >> 4;
    int row0 = blockIdx.x * 64;

    for (int c = wid; c < WCHUNKS; c += 4)
        async_copy16((const char*)Wt1 + c * 1024 + lane * 16,
                     (char*)&Wl[0] + c * 1024 + lane * 16);
    __syncthreads();

    int arow = min(row0 + wid * 16 + m16, NN - 1);
    float bb = b2[0];

    for (int l = 0; l < 3; l++) {
        const __bf16* A = stbf + (size_t)l * NF;
        f32x4 acc[8];
#pragma unroll
        for (int ct = 0; ct < 8; ct++) acc[ct] = (f32x4){0.f, 0.f, 0.f, 0.f};
#pragma unroll
        for (int kk = 0; kk < 4; kk++) {
            bf16x8 a = *(const bf16x8*)&A[(size_t)arow * D + kk * 32 + q * 8];
#pragma unroll
            for (int ct = 0; ct < 8; ct++) {
                bf16x8 b = *(const bf16x8*)&Wl[(ct * 16 + m16) * WS + kk * 32 + q * 8];
                acc[ct] = __builtin_amdgcn_mfma_f32_16x16x32_bf16(a, b, acc[ct], 0, 0, 0);
            }
        }
        float p[4] = {0.f, 0.f, 0.f, 0.f};
#pragma unroll
        for (int ct = 0; ct < 8; ct++) {
            float bv = b1[ct * 16 + m16];
            float wv = w2[ct * 16 + m16];
#pragma unroll
            for (int r = 0; r < 4; r++) p[r] += fmaxf(acc[ct][r] + bv, 0.f) * wv;
        }
#pragma unroll
        for (int r = 0; r < 4; r++) {
#pragma unroll
            for (int off = 1; off < 16; off <<= 1) p[r] += __shfl_xor(p[r], off);
            if (m16 == 0) sc_l[l][wid * 16 + q * 4 + r] = p[r] + bb;
        }
    }
    __syncthreads();

    if (t < 64) {
        int row = row0 + t;
        float s0 = sc_l[0][t], s1 = sc_l[1][t], s2 = sc_l[2][t];
        float m = fmaxf(s0, fmaxf(s1, s2));
        float e0 = expf(s0 - m), e1 = expf(s1 - m), e2 = expf(s2 - m);
        float inv = 1.f / (e0 + e1 + e2);
        lw_l[0][t] = e0 * inv;
        lw_l[1][t] = e1 * inv;
        lw_l[2][t] = e2 * inv;
        if (row < NN) {
            lw_out[row] = e0 * inv;
            lw_out[NN + row] = e1 * inv;
            lw_out[2 * NN + row] = e2 * inv;
        }
    }
    __syncthreads();

    for (int i = t; i < 64 * 32; i += 256) {
        int r = i >> 5, c4 = i & 31;
        int row = row0 + r;
        if (row >= NN) break;
        float4 v0 = ((const float4*)(st + (size_t)row * D))[c4];
        float4 v1 = ((const float4*)(st + (size_t)NF + (size_t)row * D))[c4];
        float4 v2 = ((const float4*)(st + 2 * (size_t)NF + (size_t)row * D))[c4];
        float w0 = lw_l[0][r], w1 = lw_l[1][r], w2v = lw_l[2][r];
        float4 o;
        o.x = w0 * v0.x + w1 * v1.x + w2v * v2.x;
        o.y = w0 * v0.y + w1 * v1.y + w2v * v2.y;
        o.z = w0 * v0.z + w1 * v1.z + w2v * v2.z;
        o.w = w0 * v0.w + w1 * v1.w + w2v * v2.w;
        ((float4*)(out + (size_t)row * D))[c4] = o;
    }
}

extern "C" void kernel_launch(void* const* d_in, const int* in_sizes, int n_in,
                              void* d_out, int out_size, void* d_ws, size_t ws_size,
                              hipStream_t stream) {
    const float* x = (const float*)d_in[0];
    const int* ei = (const int*)d_in[1];
    const float* conf = (const float*)d_in[2];
    const float* msg_W1 = (const float*)d_in[3];
    const float* msg_b1 = (const float*)d_in[4];
    const float* msg_W2 = (const float*)d_in[5];
    const float* msg_b2 = (const float*)d_in[6];
    const float* self_W1 = (const float*)d_in[7];
    const float* self_b1 = (const float*)d_in[8];
    const float* self_W2 = (const float*)d_in[9];
    const float* self_b2 = (const float*)d_in[10];
    const float* score_W1 = (const float*)d_in[11];
    const float* score_b1 = (const float*)d_in[12];
    const float* score_W2 = (const float*)d_in[13];
    const float* score_b2 = (const float*)d_in[14];

    float* out = (float*)d_out;                 // [NN,D]
    float* out_stacked = out + NF;              // [3,NN,D]  (canonical f32, graded)
    float* out_lw = out + 4 * (size_t)NF;       // [3,NN]

    float* w = (float*)d_ws;
    float* Mself = w;                              // NF f32
    float2* meta = (float2*)(w + (size_t)NF);      // MPAD x {src, weight} (padded CSR)
    __bf16* xbf = (__bf16*)(meta + MPAD);          // NF bf16
    __bf16* stbf = xbf + (size_t)NF;               // 3*NF bf16 (per-layer stacked)
    __bf16* Mbf = stbf + 3 * (size_t)NF;           // NF bf16 (msg MLP out, gather set)
    __bf16* wt = Mbf + (size_t)NF;                 // 13 * D * WS bf16
    int* local_rank = (int*)(wt + 13 * (size_t)D * WS);  // NE
    int* cnt_blk = local_rank + NE;                // NBLK * NN
    int* row_ptr = cnt_blk + NBLK * NN;            // NN+1
    int* cnt = row_ptr + NN + 1;                   // NN

    const size_t MAT = (size_t)D * WS;
    const int GE = (NE + 255) / 256;  // 2500
    const int GB32 = (NN + 31) / 32;  // 313
    const int GB64 = (NN + 63) / 64;  // 157

    hipMemsetAsync(meta, 0, (size_t)MPAD * sizeof(float2), stream);  // zero pad slots
    hist_prep_kernel<<<NBLK + 2513, 256, 0, stream>>>(ei, cnt_blk, local_rank,
                                                      (const float2*)x, (bf16x2*)xbf,
                                                      msg_W1, msg_W2, self_W1, self_W2,
                                                      score_W1, wt);
    colsum_kernel<<<(NN + 255) / 256, 256, 0, stream>>>(cnt_blk, cnt);
    scan_kernel<<<1, 256, 0, stream>>>(cnt, row_ptr);
    scatter_kernel<<<GE, 256, 0, stream>>>(ei, conf, local_rank, cnt_blk, row_ptr, meta);

    for (int l = 0; l < 3; l++) {
        const __bf16* a_in = (l == 0) ? xbf : stbf + (size_t)(l - 1) * NF;
        mlp_pair_mfma<<<dim3(GB32, 2), 128, 0, stream>>>(
            a_in,
            wt + (size_t)l * MAT, msg_b1 + (size_t)l * D,
            wt + (size_t)(3 + l) * MAT, msg_b2 + (size_t)l * D, Mbf,
            wt + (size_t)(6 + l) * MAT, self_b1 + (size_t)l * D,
            wt + (size_t)(9 + l) * MAT, self_b2 + (size_t)l * D, Mself);
        aggregate_kernel<<<NN / 4, 256, 0, stream>>>(
            (const uint4*)Mbf, (const float4*)Mself, row_ptr, meta,
            (float4*)(out_stacked + (size_t)l * NF),
            (bf16x8*)(stbf + (size_t)l * NF));
    }

    score_finalize_mfma<<<GB64, 256, 0, stream>>>(
        stbf, out_stacked, wt + 12 * MAT, score_b1, score_W2, score_b2, out, out_lw);
}

// Round 15
// 256.898 us; speedup vs baseline: 1.0595x; 1.0595x over previous
//
#include <hip/hip_runtime.h>

#define NN 10000
#define NE 640000
#define D 128
#define NF (NN * D)
#define WS 136   // padded bf16 row stride: 272 B = 16B-aligned, 2-way-free LDS banks
#define WBYTES (D * WS * 2)      // 34816 B per W^T matrix
#define WCHUNKS (WBYTES / 1024)  // 34 async 1KB wave-chunks
#define NBLK 100                 // hist blocks (best measured; 250 regressed via colsum)
#define EPB (NE / NBLK)          // 6400 edges per hist block
#define MPAD 1000000             // padded meta capacity: 640k + 10k*31 + slack

typedef __bf16 bf16x8 __attribute__((ext_vector_type(8)));
typedef __bf16 bf16x2 __attribute__((ext_vector_type(2)));
typedef float f32x4 __attribute__((ext_vector_type(4)));

// async global->LDS, 16B per lane, 1 KB per wave-call [m97-verified width=16]
__device__ __forceinline__ void async_copy16(const void* g, void* l) {
    __builtin_amdgcn_global_load_lds(
        (const __attribute__((address_space(1))) unsigned int*)g,
        (__attribute__((address_space(3))) unsigned int*)l, 16, 0, 0);
}

// ---------------- fused: LDS histogram | x->bf16 | W->bf16 transposed ----------------
// blocks [0,100): packed LDS histogram (2 nodes/int; per-block counts < 2^16)
// blocks [100,2600): x -> bf16 ;  blocks [2600,2613): W -> Wt[n][k]

__global__ __launch_bounds__(256) void hist_prep_kernel(
    const int* __restrict__ ei, int* __restrict__ cnt_blk, int* __restrict__ local_rank,
    const float2* __restrict__ x2, bf16x2* __restrict__ xbf,
    const float* __restrict__ mW1, const float* __restrict__ mW2,
    const float* __restrict__ sW1, const float* __restrict__ sW2,
    const float* __restrict__ scW1, __bf16* __restrict__ wt) {
    __shared__ unsigned int hist[NN / 2];   // 20 KB, 2 nodes per int
    int b = blockIdx.x, t = threadIdx.x;
    if (b < NBLK) {
        for (int i = t; i < NN / 2; i += 256) hist[i] = 0u;
        __syncthreads();
        int base = b * EPB;
#pragma unroll 1
        for (int i = 0; i < EPB / 256; i++) {
            int e = base + i * 256 + t;
            int d = ei[NE + e];
            int sh = (d & 1) * 16;
            unsigned int old = atomicAdd(&hist[d >> 1], 1u << sh);
            local_rank[e] = (old >> sh) & 0xFFFFu;
        }
        __syncthreads();
        for (int i = t; i < NN; i += 256)
            cnt_blk[b * NN + i] = (hist[i >> 1] >> ((i & 1) * 16)) & 0xFFFFu;
    } else if (b < NBLK + 2500) {
        int i = (b - NBLK) * 256 + t;   // NF/2 = 640000
        float2 v = x2[i];
        bf16x2 o;
        o.x = (__bf16)v.x;
        o.y = (__bf16)v.y;
        xbf[i] = o;
    } else {
        int m = b - (NBLK + 2500);  // 0-2 msg_W1, 3-5 msg_W2, 6-8 self_W1, 9-11 self_W2, 12 score_W1
        const float* W = (m < 3)   ? mW1 + (size_t)m * D * D
                       : (m < 6)   ? mW2 + (size_t)(m - 3) * D * D
                       : (m < 9)   ? sW1 + (size_t)(m - 6) * D * D
                       : (m < 12)  ? sW2 + (size_t)(m - 9) * D * D
                                   : scW1;
        __bf16* o = wt + (size_t)m * D * WS;
        for (int i = t; i < D * D; i += 256) {
            int k = i >> 7, n = i & 127;
            o[n * WS + k] = (__bf16)W[i];
        }
    }
}

// per-node prefix over blocks (in place) + total count; fully coalesced
__global__ void colsum_kernel(int* __restrict__ cnt_blk, int* __restrict__ cnt) {
    int n = blockIdx.x * 256 + threadIdx.x;
    if (n >= NN) return;
    int acc = 0;
#pragma unroll 4
    for (int b = 0; b < NBLK; b++) {
        int v = cnt_blk[b * NN + n];
        cnt_blk[b * NN + n] = acc;
        acc += v;
    }
    cnt[n] = acc;
}

// scan over PADDED counts (each row rounded up to 32) -> guard-free aggregate
__global__ void scan_kernel(const int* __restrict__ cnt, int* __restrict__ row_ptr) {
    __shared__ int lds[256];
    int t = threadIdx.x;
    const int CH = (NN + 255) / 256;  // 40
    int base = t * CH;
    int s = 0;
    for (int i = 0; i < CH; i++) {
        int idx = base + i;
        if (idx < NN) s += (cnt[idx] + 31) & ~31;
    }
    lds[t] = s;
    __syncthreads();
    for (int off = 1; off < 256; off <<= 1) {
        int v = (t >= off) ? lds[t - off] : 0;
        __syncthreads();
        lds[t] += v;
        __syncthreads();
    }
    int run = (t == 0) ? 0 : lds[t - 1];
    for (int i = 0; i < CH; i++) {
        int idx = base + i;
        if (idx < NN) {
            row_ptr[idx] = run;
            run += (cnt[idx] + 31) & ~31;
        }
    }
    if (t == 255) row_ptr[NN] = lds[255];
}

// atomic-free scatter into the padded CSR (pad slots pre-zeroed by memset)
__global__ void scatter_kernel(const int* __restrict__ ei, const float* __restrict__ conf,
                               const int* __restrict__ local_rank,
                               const int* __restrict__ cnt_blk,
                               const int* __restrict__ row_ptr, float2* __restrict__ meta) {
    int e = blockIdx.x * 256 + threadIdx.x;
    if (e >= NE) return;
    int s = ei[e];
    int d = ei[NE + e];
    int blk = e / EPB;   // const divide -> magic mul
    int pos = row_ptr[d] + cnt_blk[blk * NN + d] + local_rank[e];
    meta[pos] = make_float2(__int_as_float(s), expf(-fabsf(conf[s] - conf[d])));
}

// ---------------- fused 2-layer MLP via bf16 MFMA ----------------

__global__ __launch_bounds__(128) void mlp_pair_mfma(
    const __bf16* __restrict__ Abf,
    const __bf16* __restrict__ Wt1a, const float* __restrict__ b1a,
    const __bf16* __restrict__ Wt2a, const float* __restrict__ b2a, __bf16* __restrict__ Mbf,
    const __bf16* __restrict__ Wt1b, const float* __restrict__ b1b,
    const __bf16* __restrict__ Wt2b, const float* __restrict__ b2b, float* __restrict__ Cself) {
    const __bf16* Wt1 = blockIdx.y ? Wt1b : Wt1a;
    const float* b1 = blockIdx.y ? b1b : b1a;
    const __bf16* Wt2 = blockIdx.y ? Wt2b : Wt2a;
    const float* b2 = blockIdx.y ? b2b : b2a;

    __shared__ __align__(16) __bf16 Wl[2][D * WS];    // 2 x 34816 B
    __shared__ __align__(16) __bf16 Tl[2][16 * WS];   // 4352 B per wave
    int t = threadIdx.x;
    int wid = t >> 6, lane = t & 63;
    int m16 = lane & 15, q = lane >> 4;

    for (int c = wid; c < WCHUNKS; c += 2)
        async_copy16((const char*)Wt1 + c * 1024 + lane * 16,
                     (char*)&Wl[0][0] + c * 1024 + lane * 16);

    int row0 = blockIdx.x * 32 + wid * 16;
    int arow = min(row0 + m16, NN - 1);

    bf16x8 af[4];
#pragma unroll
    for (int kk = 0; kk < 4; kk++) af[kk] = *(const bf16x8*)&Abf[(size_t)arow * D + kk * 32 + q * 8];
    float b1v[8], b2v[8];
#pragma unroll
    for (int ct = 0; ct < 8; ct++) { b1v[ct] = b1[ct * 16 + m16]; b2v[ct] = b2[ct * 16 + m16]; }

    __syncthreads();   // drains W1 staging

    for (int c = wid; c < WCHUNKS; c += 2)   // W2 staging overlaps stage-1 MFMAs
        async_copy16((const char*)Wt2 + c * 1024 + lane * 16,
                     (char*)&Wl[1][0] + c * 1024 + lane * 16);

    f32x4 acc[8];
#pragma unroll
    for (int ct = 0; ct < 8; ct++) acc[ct] = (f32x4){0.f, 0.f, 0.f, 0.f};
#pragma unroll
    for (int kk = 0; kk < 4; kk++) {
#pragma unroll
        for (int ct = 0; ct < 8; ct++) {
            bf16x8 b = *(const bf16x8*)&Wl[0][(ct * 16 + m16) * WS + kk * 32 + q * 8];
            acc[ct] = __builtin_amdgcn_mfma_f32_16x16x32_bf16(af[kk], b, acc[ct], 0, 0, 0);
        }
    }
#pragma unroll
    for (int ct = 0; ct < 8; ct++) {
#pragma unroll
        for (int r = 0; r < 4; r++) {
            float v = fmaxf(acc[ct][r] + b1v[ct], 0.f);
            Tl[wid][(q * 4 + r) * WS + ct * 16 + m16] = (__bf16)v;
        }
    }
    __syncthreads();   // drains W2 staging; T is wave-private

#pragma unroll
    for (int ct = 0; ct < 8; ct++) acc[ct] = (f32x4){0.f, 0.f, 0.f, 0.f};
#pragma unroll
    for (int kk = 0; kk < 4; kk++) {
        bf16x8 a = *(const bf16x8*)&Tl[wid][m16 * WS + kk * 32 + q * 8];
#pragma unroll
        for (int ct = 0; ct < 8; ct++) {
            bf16x8 b = *(const bf16x8*)&Wl[1][(ct * 16 + m16) * WS + kk * 32 + q * 8];
            acc[ct] = __builtin_amdgcn_mfma_f32_16x16x32_bf16(a, b, acc[ct], 0, 0, 0);
        }
    }
    if (blockIdx.y == 0) {
#pragma unroll
        for (int ct = 0; ct < 8; ct++) {
#pragma unroll
            for (int r = 0; r < 4; r++) {
                int row = row0 + q * 4 + r;
                if (row < NN) Mbf[(size_t)row * D + ct * 16 + m16] = (__bf16)(acc[ct][r] + b2v[ct]);
            }
        }
    } else {
#pragma unroll
        for (int ct = 0; ct < 8; ct++) {
#pragma unroll
            for (int r = 0; r < 4; r++) {
                int row = row0 + q * 4 + r;
                if (row < NN) Cself[(size_t)row * D + ct * 16 + m16] = acc[ct][r] + b2v[ct];
            }
        }
    }
}

// ---------------- CSR aggregate: padded rows, shuffle-broadcast meta ----------------
// Best-measured r11 version: 32-edge chunks, single prefetch, shift/and unpack.
// (64-edge super-chunks regressed via VGPR pressure; cvt_pk unpack regressed.)

__global__ __launch_bounds__(256) void aggregate_kernel(
    const uint4* __restrict__ Mbf4, const float4* __restrict__ Mself4,
    const int* __restrict__ row_ptr, const float2* __restrict__ meta,
    float4* __restrict__ out4, bf16x8* __restrict__ stbf8) {
    int wid = (blockIdx.x * 256 + threadIdx.x) >> 6;   // node id (2500*4 = NN)
    int lane = threadIdx.x & 63;
    int q = lane >> 4, l4 = lane & 15, l5 = lane & 31;
    int beg = row_ptr[wid], end = row_ptr[wid + 1];
    float a[8] = {0.f, 0.f, 0.f, 0.f, 0.f, 0.f, 0.f, 0.f};
    float2 mcur = meta[beg + l5];            // chunk 0 meta (slack-safe)
    for (int j = beg; j < end; j += 32) {
        float2 mnext = meta[j + 32 + l5];    // prefetch next chunk (slack-safe)
        int srcid[8];
        float wgt[8];
#pragma unroll
        for (int u = 0; u < 8; u++) {
            int sl = 4 * u + q;
            srcid[u] = __float_as_int(__shfl(mcur.x, sl));
            wgt[u] = __shfl(mcur.y, sl);
        }
        uint4 g[8];
#pragma unroll
        for (int u = 0; u < 8; u++) g[u] = Mbf4[(size_t)srcid[u] * 16 + l4];
#pragma unroll
        for (int u = 0; u < 8; u++) {
            float w = wgt[u];
            a[0] = fmaf(w, __uint_as_float(g[u].x << 16), a[0]);
            a[1] = fmaf(w, __uint_as_float(g[u].x & 0xFFFF0000u), a[1]);
            a[2] = fmaf(w, __uint_as_float(g[u].y << 16), a[2]);
            a[3] = fmaf(w, __uint_as_float(g[u].y & 0xFFFF0000u), a[3]);
            a[4] = fmaf(w, __uint_as_float(g[u].z << 16), a[4]);
            a[5] = fmaf(w, __uint_as_float(g[u].z & 0xFFFF0000u), a[5]);
            a[6] = fmaf(w, __uint_as_float(g[u].w << 16), a[6]);
            a[7] = fmaf(w, __uint_as_float(g[u].w & 0xFFFF0000u), a[7]);
        }
        mcur = mnext;
    }
#pragma unroll
    for (int i = 0; i < 8; i++) {
        a[i] += __shfl_xor(a[i], 16);
        a[i] += __shfl_xor(a[i], 32);
    }
    if (q == 0) {   // lanes 0..15: features 8*l4 .. 8*l4+7, canonical
        float4 sv0 = Mself4[(size_t)wid * 32 + 2 * l4];
        float4 sv1 = Mself4[(size_t)wid * 32 + 2 * l4 + 1];
        float4 r0, r1;
        r0.x = fmaxf(a[0] + sv0.x, 0.f);
        r0.y = fmaxf(a[1] + sv0.y, 0.f);
        r0.z = fmaxf(a[2] + sv0.z, 0.f);
        r0.w = fmaxf(a[3] + sv0.w, 0.f);
        r1.x = fmaxf(a[4] + sv1.x, 0.f);
        r1.y = fmaxf(a[5] + sv1.y, 0.f);
        r1.z = fmaxf(a[6] + sv1.z, 0.f);
        r1.w = fmaxf(a[7] + sv1.w, 0.f);
        out4[(size_t)wid * 32 + 2 * l4] = r0;
        out4[(size_t)wid * 32 + 2 * l4 + 1] = r1;
        bf16x8 hb;
        hb[0] = (__bf16)r0.x; hb[1] = (__bf16)r0.y;
        hb[2] = (__bf16)r0.z; hb[3] = (__bf16)r0.w;
        hb[4] = (__bf16)r1.x; hb[5] = (__bf16)r1.y;
        hb[6] = (__bf16)r1.z; hb[7] = (__bf16)r1.w;
        stbf8[(size_t)wid * 16 + l4] = hb;
    }
}

// ---------------- fused scoring (MFMA) + softmax + weighted sum ----------------

__global__ __launch_bounds__(256) void score_finalize_mfma(
    const __bf16* __restrict__ stbf, const float* __restrict__ st,
    const __bf16* __restrict__ Wt1, const float* __restrict__ b1,
    const float* __restrict__ w2, const float* __restrict__ b2,
    float* __restrict__ out, float* __restrict__ lw_out) {
    __shared__ __align__(16) __bf16 Wl[D * WS];   // 34816 B
    __shared__ float sc_l[3][64];
    __shared__ float lw_l[3][64];
    int t = threadIdx.x;
    int wid = t >> 6, lane = t & 63;
    int m16 = lane & 15, q = lane >> 4;
    int row0 = blockIdx.x * 64;

    for (int c = wid; c < WCHUNKS; c += 4)
        async_copy16((const char*)Wt1 + c * 1024 + lane * 16,
                     (char*)&Wl[0] + c * 1024 + lane * 16);
    __syncthreads();

    int arow = min(row0 + wid * 16 + m16, NN - 1);
    float bb = b2[0];

    for (int l = 0; l < 3; l++) {
        const __bf16* A = stbf + (size_t)l * NF;
        f32x4 acc[8];
#pragma unroll
        for (int ct = 0; ct < 8; ct++) acc[ct] = (f32x4){0.f, 0.f, 0.f, 0.f};
#pragma unroll
        for (int kk = 0; kk < 4; kk++) {
            bf16x8 a = *(const bf16x8*)&A[(size_t)arow * D + kk * 32 + q * 8];
#pragma unroll
            for (int ct = 0; ct < 8; ct++) {
                bf16x8 b = *(const bf16x8*)&Wl[(ct * 16 + m16) * WS + kk * 32 + q * 8];
                acc[ct] = __builtin_amdgcn_mfma_f32_16x16x32_bf16(a, b, acc[ct], 0, 0, 0);
            }
        }
        float p[4] = {0.f, 0.f, 0.f, 0.f};
#pragma unroll
        for (int ct = 0; ct < 8; ct++) {
            float bv = b1[ct * 16 + m16];
            float wv = w2[ct * 16 + m16];
#pragma unroll
            for (int r = 0; r < 4; r++) p[r] += fmaxf(acc[ct][r] + bv, 0.f) * wv;
        }
#pragma unroll
        for (int r = 0; r < 4; r++) {
#pragma unroll
            for (int off = 1; off < 16; off <<= 1) p[r] += __shfl_xor(p[r], off);
            if (m16 == 0) sc_l[l][wid * 16 + q * 4 + r] = p[r] + bb;
        }
    }
    __syncthreads();

    if (t < 64) {
        int row = row0 + t;
        float s0 = sc_l[0][t], s1 = sc_l[1][t], s2 = sc_l[2][t];
        float m = fmaxf(s0, fmaxf(s1, s2));
        float e0 = expf(s0 - m), e1 = expf(s1 - m), e2 = expf(s2 - m);
        float inv = 1.f / (e0 + e1 + e2);
        lw_l[0][t] = e0 * inv;
        lw_l[1][t] = e1 * inv;
        lw_l[2][t] = e2 * inv;
        if (row < NN) {
            lw_out[row] = e0 * inv;
            lw_out[NN + row] = e1 * inv;
            lw_out[2 * NN + row] = e2 * inv;
        }
    }
    __syncthreads();

    for (int i = t; i < 64 * 32; i += 256) {
        int r = i >> 5, c4 = i & 31;
        int row = row0 + r;
        if (row >= NN) break;
        float4 v0 = ((const float4*)(st + (size_t)row * D))[c4];
        float4 v1 = ((const float4*)(st + (size_t)NF + (size_t)row * D))[c4];
        float4 v2 = ((const float4*)(st + 2 * (size_t)NF + (size_t)row * D))[c4];
        float w0 = lw_l[0][r], w1 = lw_l[1][r], w2v = lw_l[2][r];
        float4 o;
        o.x = w0 * v0.x + w1 * v1.x + w2v * v2.x;
        o.y = w0 * v0.y + w1 * v1.y + w2v * v2.y;
        o.z = w0 * v0.z + w1 * v1.z + w2v * v2.z;
        o.w = w0 * v0.w + w1 * v1.w + w2v * v2.w;
        ((float4*)(out + (size_t)row * D))[c4] = o;
    }
}

extern "C" void kernel_launch(void* const* d_in, const int* in_sizes, int n_in,
                              void* d_out, int out_size, void* d_ws, size_t ws_size,
                              hipStream_t stream) {
    const float* x = (const float*)d_in[0];
    const int* ei = (const int*)d_in[1];
    const float* conf = (const float*)d_in[2];
    const float* msg_W1 = (const float*)d_in[3];
    const float* msg_b1 = (const float*)d_in[4];
    const float* msg_W2 = (const float*)d_in[5];
    const float* msg_b2 = (const float*)d_in[6];
    const float* self_W1 = (const float*)d_in[7];
    const float* self_b1 = (const float*)d_in[8];
    const float* self_W2 = (const float*)d_in[9];
    const float* self_b2 = (const float*)d_in[10];
    const float* score_W1 = (const float*)d_in[11];
    const float* score_b1 = (const float*)d_in[12];
    const float* score_W2 = (const float*)d_in[13];
    const float* score_b2 = (const float*)d_in[14];

    float* out = (float*)d_out;                 // [NN,D]
    float* out_stacked = out + NF;              // [3,NN,D]  (canonical f32, graded)
    float* out_lw = out + 4 * (size_t)NF;       // [3,NN]

    float* w = (float*)d_ws;
    float* Mself = w;                              // NF f32
    float2* meta = (float2*)(w + (size_t)NF);      // MPAD x {src, weight} (padded CSR)
    __bf16* xbf = (__bf16*)(meta + MPAD);          // NF bf16
    __bf16* stbf = xbf + (size_t)NF;               // 3*NF bf16 (per-layer stacked)
    __bf16* Mbf = stbf + 3 * (size_t)NF;           // NF bf16 (msg MLP out, gather set)
    __bf16* wt = Mbf + (size_t)NF;                 // 13 * D * WS bf16
    int* local_rank = (int*)(wt + 13 * (size_t)D * WS);  // NE
    int* cnt_blk = local_rank + NE;                // NBLK * NN
    int* row_ptr = cnt_blk + NBLK * NN;            // NN+1
    int* cnt = row_ptr + NN + 1;                   // NN

    const size_t MAT = (size_t)D * WS;
    const int GE = (NE + 255) / 256;  // 2500
    const int GB32 = (NN + 31) / 32;  // 313
    const int GB64 = (NN + 63) / 64;  // 157

    hipMemsetAsync(meta, 0, (size_t)MPAD * sizeof(float2), stream);  // zero pad slots
    hist_prep_kernel<<<NBLK + 2513, 256, 0, stream>>>(ei, cnt_blk, local_rank,
                                                      (const float2*)x, (bf16x2*)xbf,
                                                      msg_W1, msg_W2, self_W1, self_W2,
                                                      score_W1, wt);
    colsum_kernel<<<(NN + 255) / 256, 256, 0, stream>>>(cnt_blk, cnt);
    scan_kernel<<<1, 256, 0, stream>>>(cnt, row_ptr);
    scatter_kernel<<<GE, 256, 0, stream>>>(ei, conf, local_rank, cnt_blk, row_ptr, meta);

    for (int l = 0; l < 3; l++) {
        const __bf16* a_in = (l == 0) ? xbf : stbf + (size_t)(l - 1) * NF;
        mlp_pair_mfma<<<dim3(GB32, 2), 128, 0, stream>>>(
            a_in,
            wt + (size_t)l * MAT, msg_b1 + (size_t)l * D,
            wt + (size_t)(3 + l) * MAT, msg_b2 + (size_t)l * D, Mbf,
            wt + (size_t)(6 + l) * MAT, self_b1 + (size_t)l * D,
            wt + (size_t)(9 + l) * MAT, self_b2 + (size_t)l * D, Mself);
        aggregate_kernel<<<NN / 4, 256, 0, stream>>>(
            (const uint4*)Mbf, (const float4*)Mself, row_ptr, meta,
            (float4*)(out_stacked + (size_t)l * NF),
            (bf16x8*)(stbf + (size_t)l * NF));
    }

    score_finalize_mfma<<<GB64, 256, 0, stream>>>(
        stbf, out_stacked, wt + 12 * MAT, score_b1, score_W2, score_b2, out, out_lw);
}

// Round 16
// 250.745 us; speedup vs baseline: 1.0855x; 1.0245x over previous
//
#include <hip/hip_runtime.h>

#define NN 10000
#define NE 640000
#define D 128
#define NF (NN * D)
#define WS 136   // padded bf16 row stride: 272 B = 16B-aligned, 2-way-free LDS banks
#define WBYTES (D * WS * 2)      // 34816 B per W^T matrix
#define WCHUNKS (WBYTES / 1024)  // 34 async 1KB wave-chunks
#define NBLK 100                 // hist blocks (best measured)
#define EPB (NE / NBLK)          // 6400 edges per hist block
#define MPAD 1000000             // padded meta capacity: 640k + 10k*31 + slack
#define GB32 313                 // (NN+31)/32 row-blocks for the MLP

typedef __bf16 bf16x8 __attribute__((ext_vector_type(8)));
typedef __bf16 bf16x2 __attribute__((ext_vector_type(2)));
typedef float f32x4 __attribute__((ext_vector_type(4)));

// async global->LDS, 16B per lane, 1 KB per wave-call [m97-verified width=16]
__device__ __forceinline__ void async_copy16(const void* g, void* l) {
    __builtin_amdgcn_global_load_lds(
        (const __attribute__((address_space(1))) unsigned int*)g,
        (__attribute__((address_space(3))) unsigned int*)l, 16, 0, 0);
}

// ---------------- fused: LDS histogram | x->bf16 | W->bf16 transposed ----------------

__global__ __launch_bounds__(256) void hist_prep_kernel(
    const int* __restrict__ ei, int* __restrict__ cnt_blk, int* __restrict__ local_rank,
    const float2* __restrict__ x2, bf16x2* __restrict__ xbf,
    const float* __restrict__ mW1, const float* __restrict__ mW2,
    const float* __restrict__ sW1, const float* __restrict__ sW2,
    const float* __restrict__ scW1, __bf16* __restrict__ wt) {
    __shared__ unsigned int hist[NN / 2];   // 20 KB, 2 nodes per int
    int b = blockIdx.x, t = threadIdx.x;
    if (b < NBLK) {
        for (int i = t; i < NN / 2; i += 256) hist[i] = 0u;
        __syncthreads();
        int base = b * EPB;
#pragma unroll 1
        for (int i = 0; i < EPB / 256; i++) {
            int e = base + i * 256 + t;
            int d = ei[NE + e];
            int sh = (d & 1) * 16;
            unsigned int old = atomicAdd(&hist[d >> 1], 1u << sh);
            local_rank[e] = (old >> sh) & 0xFFFFu;
        }
        __syncthreads();
        for (int i = t; i < NN; i += 256)
            cnt_blk[b * NN + i] = (hist[i >> 1] >> ((i & 1) * 16)) & 0xFFFFu;
    } else if (b < NBLK + 2500) {
        int i = (b - NBLK) * 256 + t;   // NF/2 = 640000
        float2 v = x2[i];
        bf16x2 o;
        o.x = (__bf16)v.x;
        o.y = (__bf16)v.y;
        xbf[i] = o;
    } else {
        int m = b - (NBLK + 2500);  // 0-2 msg_W1, 3-5 msg_W2, 6-8 self_W1, 9-11 self_W2, 12 score_W1
        const float* W = (m < 3)   ? mW1 + (size_t)m * D * D
                       : (m < 6)   ? mW2 + (size_t)(m - 3) * D * D
                       : (m < 9)   ? sW1 + (size_t)(m - 6) * D * D
                       : (m < 12)  ? sW2 + (size_t)(m - 9) * D * D
                                   : scW1;
        __bf16* o = wt + (size_t)m * D * WS;
        for (int i = t; i < D * D; i += 256) {
            int k = i >> 7, n = i & 127;
            o[n * WS + k] = (__bf16)W[i];
        }
    }
}

// scan over PADDED counts (each row rounded up to 32) -> guard-free aggregate
__global__ void scan_kernel(const int* __restrict__ cnt, int* __restrict__ row_ptr) {
    __shared__ int lds[256];
    int t = threadIdx.x;
    const int CH = (NN + 255) / 256;  // 40
    int base = t * CH;
    int s = 0;
    for (int i = 0; i < CH; i++) {
        int idx = base + i;
        if (idx < NN) s += (cnt[idx] + 31) & ~31;
    }
    lds[t] = s;
    __syncthreads();
    for (int off = 1; off < 256; off <<= 1) {
        int v = (t >= off) ? lds[t - off] : 0;
        __syncthreads();
        lds[t] += v;
        __syncthreads();
    }
    int run = (t == 0) ? 0 : lds[t - 1];
    for (int i = 0; i < CH; i++) {
        int idx = base + i;
        if (idx < NN) {
            row_ptr[idx] = run;
            run += (cnt[idx] + 31) & ~31;
        }
    }
    if (t == 255) row_ptr[NN] = lds[255];
}

// atomic-free scatter into the padded CSR (pad slots pre-zeroed by memset)
__global__ void scatter_kernel(const int* __restrict__ ei, const float* __restrict__ conf,
                               const int* __restrict__ local_rank,
                               const int* __restrict__ cnt_blk,
                               const int* __restrict__ row_ptr, float2* __restrict__ meta) {
    int e = blockIdx.x * 256 + threadIdx.x;
    if (e >= NE) return;
    int s = ei[e];
    int d = ei[NE + e];
    int blk = e / EPB;   // const divide -> magic mul
    int pos = row_ptr[d] + cnt_blk[blk * NN + d] + local_rank[e];
    meta[pos] = make_float2(__int_as_float(s), expf(-fabsf(conf[s] - conf[d])));
}

// ---------------- fused 2-layer MLP via bf16 MFMA (layers 1,2) ----------------

__global__ __launch_bounds__(128) void mlp_pair_mfma(
    const __bf16* __restrict__ Abf,
    const __bf16* __restrict__ Wt1a, const float* __restrict__ b1a,
    const __bf16* __restrict__ Wt2a, const float* __restrict__ b2a, __bf16* __restrict__ Mbf,
    const __bf16* __restrict__ Wt1b, const float* __restrict__ b1b,
    const __bf16* __restrict__ Wt2b, const float* __restrict__ b2b, float* __restrict__ Cself) {
    const __bf16* Wt1 = blockIdx.y ? Wt1b : Wt1a;
    const float* b1 = blockIdx.y ? b1b : b1a;
    const __bf16* Wt2 = blockIdx.y ? Wt2b : Wt2a;
    const float* b2 = blockIdx.y ? b2b : b2a;

    __shared__ __align__(16) __bf16 Wl[2][D * WS];    // 2 x 34816 B
    __shared__ __align__(16) __bf16 Tl[2][16 * WS];   // 4352 B per wave
    int t = threadIdx.x;
    int wid = t >> 6, lane = t & 63;
    int m16 = lane & 15, q = lane >> 4;

    for (int c = wid; c < WCHUNKS; c += 2)
        async_copy16((const char*)Wt1 + c * 1024 + lane * 16,
                     (char*)&Wl[0][0] + c * 1024 + lane * 16);

    int row0 = blockIdx.x * 32 + wid * 16;
    int arow = min(row0 + m16, NN - 1);

    bf16x8 af[4];
#pragma unroll
    for (int kk = 0; kk < 4; kk++) af[kk] = *(const bf16x8*)&Abf[(size_t)arow * D + kk * 32 + q * 8];
    float b1v[8], b2v[8];
#pragma unroll
    for (int ct = 0; ct < 8; ct++) { b1v[ct] = b1[ct * 16 + m16]; b2v[ct] = b2[ct * 16 + m16]; }

    __syncthreads();   // drains W1 staging

    for (int c = wid; c < WCHUNKS; c += 2)   // W2 staging overlaps stage-1 MFMAs
        async_copy16((const char*)Wt2 + c * 1024 + lane * 16,
                     (char*)&Wl[1][0] + c * 1024 + lane * 16);

    f32x4 acc[8];
#pragma unroll
    for (int ct = 0; ct < 8; ct++) acc[ct] = (f32x4){0.f, 0.f, 0.f, 0.f};
#pragma unroll
    for (int kk = 0; kk < 4; kk++) {
#pragma unroll
        for (int ct = 0; ct < 8; ct++) {
            bf16x8 b = *(const bf16x8*)&Wl[0][(ct * 16 + m16) * WS + kk * 32 + q * 8];
            acc[ct] = __builtin_amdgcn_mfma_f32_16x16x32_bf16(af[kk], b, acc[ct], 0, 0, 0);
        }
    }
#pragma unroll
    for (int ct = 0; ct < 8; ct++) {
#pragma unroll
        for (int r = 0; r < 4; r++) {
            float v = fmaxf(acc[ct][r] + b1v[ct], 0.f);
            Tl[wid][(q * 4 + r) * WS + ct * 16 + m16] = (__bf16)v;
        }
    }
    __syncthreads();   // drains W2 staging; T is wave-private

#pragma unroll
    for (int ct = 0; ct < 8; ct++) acc[ct] = (f32x4){0.f, 0.f, 0.f, 0.f};
#pragma unroll
    for (int kk = 0; kk < 4; kk++) {
        bf16x8 a = *(const bf16x8*)&Tl[wid][m16 * WS + kk * 32 + q * 8];
#pragma unroll
        for (int ct = 0; ct < 8; ct++) {
            bf16x8 b = *(const bf16x8*)&Wl[1][(ct * 16 + m16) * WS + kk * 32 + q * 8];
            acc[ct] = __builtin_amdgcn_mfma_f32_16x16x32_bf16(a, b, acc[ct], 0, 0, 0);
        }
    }
    if (blockIdx.y == 0) {
#pragma unroll
        for (int ct = 0; ct < 8; ct++) {
#pragma unroll
            for (int r = 0; r < 4; r++) {
                int row = row0 + q * 4 + r;
                if (row < NN) Mbf[(size_t)row * D + ct * 16 + m16] = (__bf16)(acc[ct][r] + b2v[ct]);
            }
        }
    } else {
#pragma unroll
        for (int ct = 0; ct < 8; ct++) {
#pragma unroll
            for (int r = 0; r < 4; r++) {
                int row = row0 + q * 4 + r;
                if (row < NN) Cself[(size_t)row * D + ct * 16 + m16] = acc[ct][r] + b2v[ct];
            }
        }
    }
}

// ---------------- fused layer-0 MLP + colsum ----------------
// Blocks [0,626): the unchanged mlp0 body (msg = [0,313), self = [313,626)).
// Blocks [626,705): colsum at 128 threads (79 blocks < 256 CUs, so the static
// LDS allocation cannot reduce colsum's residency). colsum and mlp0 are
// dependency-independent siblings of hist_prep — overlapping them hides
// colsum entirely and drops one launch gap.

__global__ __launch_bounds__(128) void mlp0_colsum_kernel(
    const __bf16* __restrict__ Abf,
    const __bf16* __restrict__ Wt1a, const float* __restrict__ b1a,
    const __bf16* __restrict__ Wt2a, const float* __restrict__ b2a, __bf16* __restrict__ Mbf,
    const __bf16* __restrict__ Wt1b, const float* __restrict__ b1b,
    const __bf16* __restrict__ Wt2b, const float* __restrict__ b2b, float* __restrict__ Cself,
    int* __restrict__ cnt_blk, int* __restrict__ cnt) {
    __shared__ __align__(16) __bf16 Wl[2][D * WS];    // 2 x 34816 B
    __shared__ __align__(16) __bf16 Tl[2][16 * WS];   // 4352 B per wave
    int b = blockIdx.x, t = threadIdx.x;

    if (b >= 2 * GB32) {   // ---- colsum portion ----
        int n = (b - 2 * GB32) * 128 + t;
        if (n >= NN) return;
        int acc = 0;
#pragma unroll 4
        for (int blk = 0; blk < NBLK; blk++) {
            int v = cnt_blk[blk * NN + n];
            cnt_blk[blk * NN + n] = acc;
            acc += v;
        }
        cnt[n] = acc;
        return;
    }

    // ---- mlp0 portion (identical body; problem select by block range) ----
    int pb = (b >= GB32);
    int bx = pb ? b - GB32 : b;
    const __bf16* Wt1 = pb ? Wt1b : Wt1a;
    const float* b1 = pb ? b1b : b1a;
    const __bf16* Wt2 = pb ? Wt2b : Wt2a;
    const float* b2 = pb ? b2b : b2a;

    int wid = t >> 6, lane = t & 63;
    int m16 = lane & 15, q = lane >> 4;

    for (int c = wid; c < WCHUNKS; c += 2)
        async_copy16((const char*)Wt1 + c * 1024 + lane * 16,
                     (char*)&Wl[0][0] + c * 1024 + lane * 16);

    int row0 = bx * 32 + wid * 16;
    int arow = min(row0 + m16, NN - 1);

    bf16x8 af[4];
#pragma unroll
    for (int kk = 0; kk < 4; kk++) af[kk] = *(const bf16x8*)&Abf[(size_t)arow * D + kk * 32 + q * 8];
    float b1v[8], b2v[8];
#pragma unroll
    for (int ct = 0; ct < 8; ct++) { b1v[ct] = b1[ct * 16 + m16]; b2v[ct] = b2[ct * 16 + m16]; }

    __syncthreads();   // drains W1 staging

    for (int c = wid; c < WCHUNKS; c += 2)
        async_copy16((const char*)Wt2 + c * 1024 + lane * 16,
                     (char*)&Wl[1][0] + c * 1024 + lane * 16);

    f32x4 acc[8];
#pragma unroll
    for (int ct = 0; ct < 8; ct++) acc[ct] = (f32x4){0.f, 0.f, 0.f, 0.f};
#pragma unroll
    for (int kk = 0; kk < 4; kk++) {
#pragma unroll
        for (int ct = 0; ct < 8; ct++) {
            bf16x8 bb = *(const bf16x8*)&Wl[0][(ct * 16 + m16) * WS + kk * 32 + q * 8];
            acc[ct] = __builtin_amdgcn_mfma_f32_16x16x32_bf16(af[kk], bb, acc[ct], 0, 0, 0);
        }
    }
#pragma unroll
    for (int ct = 0; ct < 8; ct++) {
#pragma unroll
        for (int r = 0; r < 4; r++) {
            float v = fmaxf(acc[ct][r] + b1v[ct], 0.f);
            Tl[wid][(q * 4 + r) * WS + ct * 16 + m16] = (__bf16)v;
        }
    }
    __syncthreads();   // drains W2 staging; T is wave-private

#pragma unroll
    for (int ct = 0; ct < 8; ct++) acc[ct] = (f32x4){0.f, 0.f, 0.f, 0.f};
#pragma unroll
    for (int kk = 0; kk < 4; kk++) {
        bf16x8 a = *(const bf16x8*)&Tl[wid][m16 * WS + kk * 32 + q * 8];
#pragma unroll
        for (int ct = 0; ct < 8; ct++) {
            bf16x8 bb = *(const bf16x8*)&Wl[1][(ct * 16 + m16) * WS + kk * 32 + q * 8];
            acc[ct] = __builtin_amdgcn_mfma_f32_16x16x32_bf16(a, bb, acc[ct], 0, 0, 0);
        }
    }
    if (pb == 0) {
#pragma unroll
        for (int ct = 0; ct < 8; ct++) {
#pragma unroll
            for (int r = 0; r < 4; r++) {
                int row = row0 + q * 4 + r;
                if (row < NN) Mbf[(size_t)row * D + ct * 16 + m16] = (__bf16)(acc[ct][r] + b2v[ct]);
            }
        }
    } else {
#pragma unroll
        for (int ct = 0; ct < 8; ct++) {
#pragma unroll
            for (int r = 0; r < 4; r++) {
                int row = row0 + q * 4 + r;
                if (row < NN) Cself[(size_t)row * D + ct * 16 + m16] = acc[ct][r] + b2v[ct];
            }
        }
    }
}

// ---------------- CSR aggregate: padded rows, shuffle-broadcast meta ----------------

__global__ __launch_bounds__(256) void aggregate_kernel(
    const uint4* __restrict__ Mbf4, const float4* __restrict__ Mself4,
    const int* __restrict__ row_ptr, const float2* __restrict__ meta,
    float4* __restrict__ out4, bf16x8* __restrict__ stbf8) {
    int wid = (blockIdx.x * 256 + threadIdx.x) >> 6;   // node id (2500*4 = NN)
    int lane = threadIdx.x & 63;
    int q = lane >> 4, l4 = lane & 15, l5 = lane & 31;
    int beg = row_ptr[wid], end = row_ptr[wid + 1];
    float a[8] = {0.f, 0.f, 0.f, 0.f, 0.f, 0.f, 0.f, 0.f};
    float2 mcur = meta[beg + l5];            // chunk 0 meta (slack-safe)
    for (int j = beg; j < end; j += 32) {
        float2 mnext = meta[j + 32 + l5];    // prefetch next chunk (slack-safe)
        int srcid[8];
        float wgt[8];
#pragma unroll
        for (int u = 0; u < 8; u++) {
            int sl = 4 * u + q;
            srcid[u] = __float_as_int(__shfl(mcur.x, sl));
            wgt[u] = __shfl(mcur.y, sl);
        }
        uint4 g[8];
#pragma unroll
        for (int u = 0; u < 8; u++) g[u] = Mbf4[(size_t)srcid[u] * 16 + l4];
#pragma unroll
        for (int u = 0; u < 8; u++) {
            float w = wgt[u];
            a[0] = fmaf(w, __uint_as_float(g[u].x << 16), a[0]);
            a[1] = fmaf(w, __uint_as_float(g[u].x & 0xFFFF0000u), a[1]);
            a[2] = fmaf(w, __uint_as_float(g[u].y << 16), a[2]);
            a[3] = fmaf(w, __uint_as_float(g[u].y & 0xFFFF0000u), a[3]);
            a[4] = fmaf(w, __uint_as_float(g[u].z << 16), a[4]);
            a[5] = fmaf(w, __uint_as_float(g[u].z & 0xFFFF0000u), a[5]);
            a[6] = fmaf(w, __uint_as_float(g[u].w << 16), a[6]);
            a[7] = fmaf(w, __uint_as_float(g[u].w & 0xFFFF0000u), a[7]);
        }
        mcur = mnext;
    }
#pragma unroll
    for (int i = 0; i < 8; i++) {
        a[i] += __shfl_xor(a[i], 16);
        a[i] += __shfl_xor(a[i], 32);
    }
    if (q == 0) {   // lanes 0..15: features 8*l4 .. 8*l4+7, canonical
        float4 sv0 = Mself4[(size_t)wid * 32 + 2 * l4];
        float4 sv1 = Mself4[(size_t)wid * 32 + 2 * l4 + 1];
        float4 r0, r1;
        r0.x = fmaxf(a[0] + sv0.x, 0.f);
        r0.y = fmaxf(a[1] + sv0.y, 0.f);
        r0.z = fmaxf(a[2] + sv0.z, 0.f);
        r0.w = fmaxf(a[3] + sv0.w, 0.f);
        r1.x = fmaxf(a[4] + sv1.x, 0.f);
        r1.y = fmaxf(a[5] + sv1.y, 0.f);
        r1.z = fmaxf(a[6] + sv1.z, 0.f);
        r1.w = fmaxf(a[7] + sv1.w, 0.f);
        out4[(size_t)wid * 32 + 2 * l4] = r0;
        out4[(size_t)wid * 32 + 2 * l4 + 1] = r1;
        bf16x8 hb;
        hb[0] = (__bf16)r0.x; hb[1] = (__bf16)r0.y;
        hb[2] = (__bf16)r0.z; hb[3] = (__bf16)r0.w;
        hb[4] = (__bf16)r1.x; hb[5] = (__bf16)r1.y;
        hb[6] = (__bf16)r1.z; hb[7] = (__bf16)r1.w;
        stbf8[(size_t)wid * 16 + l4] = hb;
    }
}

// ---------------- fused scoring (MFMA) + softmax + weighted sum ----------------

__global__ __launch_bounds__(256) void score_finalize_mfma(
    const __bf16* __restrict__ stbf, const float* __restrict__ st,
    const __bf16* __restrict__ Wt1, const float* __restrict__ b1,
    const float* __restrict__ w2, const float* __restrict__ b2,
    float* __restrict__ out, float* __restrict__ lw_out) {
    __shared__ __align__(16) __bf16 Wl[D * WS];   // 34816 B
    __shared__ float sc_l[3][64];
    __shared__ float lw_l[3][64];
    int t = threadIdx.x;
    int wid = t >> 6, lane = t & 63;
    int m16 = lane & 15, q = lane >> 4;
    int row0 = blockIdx.x * 64;

    for (int c = wid; c < WCHUNKS; c += 4)
        async_copy16((const char*)Wt1 + c * 1024 + lane * 16,
                     (char*)&Wl[0] + c * 1024 + lane * 16);
    __syncthreads();

    int arow = min(row0 + wid * 16 + m16, NN - 1);
    float bb = b2[0];

    for (int l = 0; l < 3; l++) {
        const __bf16* A = stbf + (size_t)l * NF;
        f32x4 acc[8];
#pragma unroll
        for (int ct = 0; ct < 8; ct++) acc[ct] = (f32x4){0.f, 0.f, 0.f, 0.f};
#pragma unroll
        for (int kk = 0; kk < 4; kk++) {
            bf16x8 a = *(const bf16x8*)&A[(size_t)arow * D + kk * 32 + q * 8];
#pragma unroll
            for (int ct = 0; ct < 8; ct++) {
                bf16x8 b = *(const bf16x8*)&Wl[(ct * 16 + m16) * WS + kk * 32 + q * 8];
                acc[ct] = __builtin_amdgcn_mfma_f32_16x16x32_bf16(a, b, acc[ct], 0, 0, 0);
            }
        }
        float p[4] = {0.f, 0.f, 0.f, 0.f};
#pragma unroll
        for (int ct = 0; ct < 8; ct++) {
            float bv = b1[ct * 16 + m16];
            float wv = w2[ct * 16 + m16];
#pragma unroll
            for (int r = 0; r < 4; r++) p[r] += fmaxf(acc[ct][r] + bv, 0.f) * wv;
        }
#pragma unroll
        for (int r = 0; r < 4; r++) {
#pragma unroll
            for (int off = 1; off < 16; off <<= 1) p[r] += __shfl_xor(p[r], off);
            if (m16 == 0) sc_l[l][wid * 16 + q * 4 + r] = p[r] + bb;
        }
    }
    __syncthreads();

    if (t < 64) {
        int row = row0 + t;
        float s0 = sc_l[0][t], s1 = sc_l[1][t], s2 = sc_l[2][t];
        float m = fmaxf(s0, fmaxf(s1, s2));
        float e0 = expf(s0 - m), e1 = expf(s1 - m), e2 = expf(s2 - m);
        float inv = 1.f / (e0 + e1 + e2);
        lw_l[0][t] = e0 * inv;
        lw_l[1][t] = e1 * inv;
        lw_l[2][t] = e2 * inv;
        if (row < NN) {
            lw_out[row] = e0 * inv;
            lw_out[NN + row] = e1 * inv;
            lw_out[2 * NN + row] = e2 * inv;
        }
    }
    __syncthreads();

    for (int i = t; i < 64 * 32; i += 256) {
        int r = i >> 5, c4 = i & 31;
        int row = row0 + r;
        if (row >= NN) break;
        float4 v0 = ((const float4*)(st + (size_t)row * D))[c4];
        float4 v1 = ((const float4*)(st + (size_t)NF + (size_t)row * D))[c4];
        float4 v2 = ((const float4*)(st + 2 * (size_t)NF + (size_t)row * D))[c4];
        float w0 = lw_l[0][r], w1 = lw_l[1][r], w2v = lw_l[2][r];
        float4 o;
        o.x = w0 * v0.x + w1 * v1.x + w2v * v2.x;
        o.y = w0 * v0.y + w1 * v1.y + w2v * v2.y;
        o.z = w0 * v0.z + w1 * v1.z + w2v * v2.z;
        o.w = w0 * v0.w + w1 * v1.w + w2v * v2.w;
        ((float4*)(out + (size_t)row * D))[c4] = o;
    }
}

extern "C" void kernel_launch(void* const* d_in, const int* in_sizes, int n_in,
                              void* d_out, int out_size, void* d_ws, size_t ws_size,
                              hipStream_t stream) {
    const float* x = (const float*)d_in[0];
    const int* ei = (const int*)d_in[1];
    const float* conf = (const float*)d_in[2];
    const float* msg_W1 = (const float*)d_in[3];
    const float* msg_b1 = (const float*)d_in[4];
    const float* msg_W2 = (const float*)d_in[5];
    const float* msg_b2 = (const float*)d_in[6];
    const float* self_W1 = (const float*)d_in[7];
    const float* self_b1 = (const float*)d_in[8];
    const float* self_W2 = (const float*)d_in[9];
    const float* self_b2 = (const float*)d_in[10];
    const float* score_W1 = (const float*)d_in[11];
    const float* score_b1 = (const float*)d_in[12];
    const float* score_W2 = (const float*)d_in[13];
    const float* score_b2 = (const float*)d_in[14];

    float* out = (float*)d_out;                 // [NN,D]
    float* out_stacked = out + NF;              // [3,NN,D]  (canonical f32, graded)
    float* out_lw = out + 4 * (size_t)NF;       // [3,NN]

    float* w = (float*)d_ws;
    float* Mself = w;                              // NF f32
    float2* meta = (float2*)(w + (size_t)NF);      // MPAD x {src, weight} (padded CSR)
    __bf16* xbf = (__bf16*)(meta + MPAD);          // NF bf16
    __bf16* stbf = xbf + (size_t)NF;               // 3*NF bf16 (per-layer stacked)
    __bf16* Mbf = stbf + 3 * (size_t)NF;           // NF bf16 (msg MLP out, gather set)
    __bf16* wt = Mbf + (size_t)NF;                 // 13 * D * WS bf16
    int* local_rank = (int*)(wt + 13 * (size_t)D * WS);  // NE
    int* cnt_blk = local_rank + NE;                // NBLK * NN
    int* row_ptr = cnt_blk + NBLK * NN;            // NN+1
    int* cnt = row_ptr + NN + 1;                   // NN

    const size_t MAT = (size_t)D * WS;
    const int GE = (NE + 255) / 256;  // 2500
    const int GB64 = (NN + 63) / 64;  // 157
    const int GCS = (NN + 127) / 128; // 79 colsum blocks

    hipMemsetAsync(meta, 0, (size_t)MPAD * sizeof(float2), stream);  // zero pad slots
    hist_prep_kernel<<<NBLK + 2513, 256, 0, stream>>>(ei, cnt_blk, local_rank,
                                                      (const float2*)x, (bf16x2*)xbf,
                                                      msg_W1, msg_W2, self_W1, self_W2,
                                                      score_W1, wt);
    // layer-0 MLP overlapped with colsum (independent siblings of hist_prep)
    mlp0_colsum_kernel<<<2 * GB32 + GCS, 128, 0, stream>>>(
        xbf,
        wt + 0 * MAT, msg_b1, wt + 3 * MAT, msg_b2, Mbf,
        wt + 6 * MAT, self_b1, wt + 9 * MAT, self_b2, Mself,
        cnt_blk, cnt);
    scan_kernel<<<1, 256, 0, stream>>>(cnt, row_ptr);
    scatter_kernel<<<GE, 256, 0, stream>>>(ei, conf, local_rank, cnt_blk, row_ptr, meta);
    aggregate_kernel<<<NN / 4, 256, 0, stream>>>(
        (const uint4*)Mbf, (const float4*)Mself, row_ptr, meta,
        (float4*)(out_stacked + 0 * (size_t)NF), (bf16x8*)(stbf + 0 * (size_t)NF));

    for (int l = 1; l < 3; l++) {
        const __bf16* a_in = stbf + (size_t)(l - 1) * NF;
        mlp_pair_mfma<<<dim3(GB32, 2), 128, 0, stream>>>(
            a_in,
            wt + (size_t)l * MAT, msg_b1 + (size_t)l * D,
            wt + (size_t)(3 + l) * MAT, msg_b2 + (size_t)l * D, Mbf,
            wt + (size_t)(6 + l) * MAT, self_b1 + (size_t)l * D,
            wt + (size_t)(9 + l) * MAT, self_b2 + (size_t)l * D, Mself);
        aggregate_kernel<<<NN / 4, 256, 0, stream>>>(
            (const uint4*)Mbf, (const float4*)Mself, row_ptr, meta,
            (float4*)(out_stacked + (size_t)l * NF),
            (bf16x8*)(stbf + (size_t)l * NF));
    }

    score_finalize_mfma<<<GB64, 256, 0, stream>>>(
        stbf, out_stacked, wt + 12 * MAT, score_b1, score_W2, score_b2, out, out_lw);
}